// Round 17
// baseline (143.434 us; speedup 1.0000x reference)
//
#include <hip/hip_runtime.h>

#define N_NODES 100000
#define N_EDGES 3200000
#define F_IN 64
#define F_OUT 128

#define BSHIFT 7
#define BKT_NODES 128                                   // nodes per bucket
#define NBKT ((N_NODES + BKT_NODES - 1) / BKT_NODES)    // 782
#define CAP2 4736                                       // mean 4096 + 10 sigma

#define PART_BLOCKS 256
#define PART_THREADS 1024
#define CHUNK (N_EDGES / PART_BLOCKS)                   // 12500 exactly
#define PRPT ((CHUNK + PART_THREADS - 1) / PART_THREADS) // 13

#define SORT_THREADS 512
#define RPT 10                                          // ceil(CAP2/512)

__device__ __forceinline__ unsigned short f2bf(float f) {
    unsigned x = __float_as_uint(f);
    return (unsigned short)((x + 0x7FFFu + ((x >> 16) & 1u)) >> 16);   // RNE
}
__device__ __forceinline__ float bf2f(unsigned short h) {
    return __uint_as_float(((unsigned)h) << 16);
}
__device__ __forceinline__ unsigned bf15(float f) {      // w in [0,1): sign bit 0
    unsigned x = __float_as_uint(f);
    return ((x + 0x7FFFu + ((x >> 16) & 1u)) >> 16) & 0x7FFFu;
}

// ---- Phase 1: X->bf16 slice + bucket partition with in-LDS block sort -------
// sbkt[] eliminated (25 KB): write-out recovers the bucket by binary search
// over lstart (runs tile [0,CHUNK), last b with lstart[b] <= i). LDS ~79 KB
// -> 2 blocks/CU (was 95.7 KB -> 1 block/CU).
__global__ __launch_bounds__(PART_THREADS) void k_part(const float* __restrict__ X,
                                                       unsigned short* __restrict__ Xh,
                                                       const int* __restrict__ ei,
                                                       const float* __restrict__ ew,
                                                       unsigned* __restrict__ bcur,
                                                       unsigned* __restrict__ pack4,
                                                       unsigned char* __restrict__ dloc8) {
    __shared__ unsigned spack[CHUNK];                    // 50 KB
    __shared__ unsigned char sdl[CHUNK];                 // 12.5 KB
    __shared__ unsigned pcnt[NBKT];
    __shared__ unsigned lstart[NBKT];
    __shared__ unsigned lcur[NBKT];
    __shared__ unsigned rbase[NBKT];
    __shared__ unsigned sscan[PART_THREADS];             // 4 KB
    const int t = threadIdx.x;
    const int e0 = blockIdx.x * CHUNK;

    // phase 0: convert this block's 1/256 slice of X to bf16
    {
        const int per = (N_NODES * F_IN / 4) / PART_BLOCKS;   // 6250 float4s
        const int s0 = blockIdx.x * per;
        for (int i = t; i < per; i += PART_THREADS) {
            float4 v = ((const float4*)X)[s0 + i];
            ushort4 h;
            h.x = f2bf(v.x); h.y = f2bf(v.y); h.z = f2bf(v.z); h.w = f2bf(v.w);
            ((ushort4*)Xh)[s0 + i] = h;
        }
    }

    for (int i = t; i < NBKT; i += PART_THREADS) { pcnt[i] = 0u; lcur[i] = 0u; }
    __syncthreads();

    unsigned rp[PRPT], rm[PRPT];
    #pragma unroll
    for (int j = 0; j < PRPT; ++j) {
        int i = t + j * PART_THREADS;
        if (i < CHUNK) {
            int dst = __builtin_nontemporal_load(&ei[e0 + i]);
            int src = __builtin_nontemporal_load(&ei[N_EDGES + e0 + i]);
            float w = __builtin_nontemporal_load(&ew[e0 + i]);
            rp[j] = ((unsigned)src << 15) | bf15(w);
            unsigned b = (unsigned)dst >> BSHIFT;
            rm[j] = (b << 7) | ((unsigned)dst & (BKT_NODES - 1));
            atomicAdd(&pcnt[b], 1u);
        }
    }
    __syncthreads();

    unsigned v = (t < NBKT) ? pcnt[t] : 0u;
    sscan[t] = v;
    __syncthreads();
    for (int off = 1; off < PART_THREADS; off <<= 1) {
        unsigned u = (t >= off) ? sscan[t - off] : 0u;
        __syncthreads();
        sscan[t] += u;
        __syncthreads();
    }
    if (t < NBKT) {
        lstart[t] = sscan[t] - v;
        rbase[t]  = v ? atomicAdd(&bcur[t], v) : 0u;     // bulk reserve
    }
    __syncthreads();

    #pragma unroll
    for (int j = 0; j < PRPT; ++j) {
        int i = t + j * PART_THREADS;
        if (i < CHUNK) {
            unsigned b = rm[j] >> 7;
            unsigned slot = lstart[b] + atomicAdd(&lcur[b], 1u);
            spack[slot] = rp[j];
            sdl[slot]   = (unsigned char)(rm[j] & (BKT_NODES - 1));
        }
    }
    __syncthreads();

    // coalesced write-out; bucket of slot i = last b with lstart[b] <= i
    for (int i = t; i < CHUNK; i += PART_THREADS) {
        unsigned lo = 0, hi = NBKT - 1;
        while (lo < hi) {
            unsigned mid = (lo + hi + 1) >> 1;
            if (lstart[mid] <= (unsigned)i) lo = mid; else hi = mid - 1;
        }
        unsigned b = lo;
        unsigned dest = rbase[b] + ((unsigned)i - lstart[b]);
        if (dest < CAP2) {                               // overflow guard (p ~ 1e-18)
            pack4[(size_t)b * CAP2 + dest] = spack[i];
            dloc8[(size_t)b * CAP2 + dest] = sdl[i];
        }
    }
}

// ---- Phase 2: per-bucket node sort (packed recs, in place) ------------------
__global__ __launch_bounds__(SORT_THREADS) void k_sort(unsigned* __restrict__ pack4,
                                                       const unsigned char* __restrict__ dloc8,
                                                       const unsigned* __restrict__ bcnt,
                                                       unsigned* __restrict__ nbase,
                                                       unsigned* __restrict__ ndeg) {
    __shared__ unsigned srec[CAP2];                      // 18.9 KB
    __shared__ unsigned lcnt[BKT_NODES];
    __shared__ unsigned sincl[BKT_NODES];
    __shared__ unsigned lcur[BKT_NODES];
    const int t = threadIdx.x;
    const int b = blockIdx.x;
    unsigned cnt = bcnt[b];
    if (cnt > CAP2) cnt = CAP2;
    unsigned* run = pack4 + (size_t)b * CAP2;
    const unsigned char* drun = dloc8 + (size_t)b * CAP2;

    if (t < BKT_NODES) { lcnt[t] = 0u; lcur[t] = 0u; }
    __syncthreads();

    unsigned rp[RPT], rd[RPT];
    #pragma unroll
    for (int j = 0; j < RPT; ++j) {
        unsigned i = t + j * SORT_THREADS;
        if (i < cnt) {
            rp[j] = run[i];
            rd[j] = drun[i];
            atomicAdd(&lcnt[rd[j]], 1u);
        }
    }
    __syncthreads();

    if (t < BKT_NODES) sincl[t] = lcnt[t];
    __syncthreads();
    for (int off = 1; off < BKT_NODES; off <<= 1) {
        unsigned u = (t < BKT_NODES && t >= off) ? sincl[t - off] : 0u;
        __syncthreads();
        if (t < BKT_NODES) sincl[t] += u;
        __syncthreads();
    }

    #pragma unroll
    for (int j = 0; j < RPT; ++j) {
        unsigned i = t + j * SORT_THREADS;
        if (i < cnt) {
            unsigned nl = rd[j];
            unsigned slot = sincl[nl] - lcnt[nl] + atomicAdd(&lcur[nl], 1u);
            srec[slot] = rp[j];
        }
    }
    __syncthreads();

    for (unsigned i = t; i < cnt; i += SORT_THREADS) run[i] = srec[i];   // coalesced
    if (t < BKT_NODES) {
        int node = (b << BSHIFT) + t;
        if (node < N_NODES) {
            nbase[node] = (unsigned)b * CAP2 + sincl[t] - lcnt[t];       // uint units
            ndeg[node]  = lcnt[t];
        }
    }
}

// ---- Phase 3: one wave per node; 16-deep load pipeline (r15, proven) --------
__global__ __launch_bounds__(256) void k_gather(const unsigned short* __restrict__ Xh,
                                                const unsigned* __restrict__ recs,
                                                const unsigned* __restrict__ nbase,
                                                const unsigned* __restrict__ ndeg,
                                                unsigned short* __restrict__ Ah) {
    const int node = (blockIdx.x * 256 + threadIdx.x) >> 6;   // 25000*4 == N_NODES
    const int lane = threadIdx.x & 63;
    const unsigned i0 = nbase[node];
    const unsigned d  = ndeg[node];

    float acc = 0.f;
    if (d <= 64u) {                                      // wave-uniform branch (~always)
        unsigned p0 = 0u;
        if (lane < (int)d) p0 = recs[i0 + lane];         // one coalesced load
        for (unsigned i = 0; i < d; i += 16) {
            unsigned pk[16];
            #pragma unroll
            for (int q = 0; q < 16; ++q)
                pk[q] = (unsigned)__builtin_amdgcn_readlane((int)p0, (int)(i + q));
            float v[16];
            #pragma unroll
            for (int q = 0; q < 16; ++q)
                v[q] = bf2f(Xh[(size_t)(pk[q] >> 15) * F_IN + lane]);
            #pragma unroll
            for (int q = 0; q < 16; ++q)
                acc = fmaf(v[q], __uint_as_float((pk[q] & 0x7FFFu) << 16), acc);
        }
    } else {                                             // rare (P ~ 1e-8 per node)
        for (unsigned i = 0; i < d; ++i) {
            unsigned pk = recs[i0 + i];
            acc = fmaf(bf2f(Xh[(size_t)(pk >> 15) * F_IN + lane]),
                       __uint_as_float((pk & 0x7FFFu) << 16), acc);
        }
    }
    Ah[(size_t)node * F_IN + lane] = f2bf(acc);
}

// ---- Phase 4: projection + bias + ReLU, 16 nodes/block (bf16 A in) ----------
__global__ __launch_bounds__(256) void k_proj(const unsigned short* __restrict__ Ah,
                                              const float* __restrict__ W,
                                              const float* __restrict__ bias,
                                              float* __restrict__ out) {
    __shared__ float arows[16 * F_IN];                   // 4 KB
    const int t = threadIdx.x;
    const int node0 = blockIdx.x * 16;                   // 6250 blocks exactly
    {
        ushort4 h = ((const ushort4*)(Ah + (size_t)node0 * F_IN))[t];   // 256*4 = 1024
        float4 f;
        f.x = bf2f(h.x); f.y = bf2f(h.y); f.z = bf2f(h.z); f.w = bf2f(h.w);
        ((float4*)arows)[t] = f;
    }
    __syncthreads();

    const int f = t & 127;
    const int g = t >> 7;                                // 0..1, 8 nodes each
    float wcol[F_IN];
    #pragma unroll
    for (int k = 0; k < F_IN; ++k) wcol[k] = W[k * F_OUT + f];   // coalesced
    const float bf = bias[f];
    for (int n = g * 8; n < g * 8 + 8; ++n) {
        float acc = bf;
        #pragma unroll
        for (int k4 = 0; k4 < F_IN / 4; ++k4) {
            float4 a4 = *(const float4*)&arows[n * F_IN + k4 * 4];
            acc = fmaf(a4.x, wcol[k4 * 4 + 0], acc);
            acc = fmaf(a4.y, wcol[k4 * 4 + 1], acc);
            acc = fmaf(a4.z, wcol[k4 * 4 + 2], acc);
            acc = fmaf(a4.w, wcol[k4 * 4 + 3], acc);
        }
        out[(size_t)(node0 + n) * F_OUT + f] = fmaxf(acc, 0.f);
    }
}

// ---------------- Fallback (round-1 path) if workspace too small --------------
__global__ __launch_bounds__(256) void gcn_scatter_fb(const float* __restrict__ X,
                                                      const int* __restrict__ ei,
                                                      const float* __restrict__ ew,
                                                      float* __restrict__ A) {
    const int lane = threadIdx.x & 63;
    const int wave = (blockIdx.x * blockDim.x + threadIdx.x) >> 6;
    const int nW = (gridDim.x * blockDim.x) >> 6;
    for (int e = wave; e < N_EDGES; e += nW) {
        const int dst = ei[e];
        const int src = ei[N_EDGES + e];
        atomicAdd(&A[dst * F_IN + lane], X[src * F_IN + lane] * ew[e]);
    }
}
__global__ __launch_bounds__(128) void gcn_proj_fb(const float* __restrict__ A,
                                                   const float* __restrict__ W,
                                                   const float* __restrict__ bias,
                                                   float* __restrict__ out) {
    __shared__ float arow[F_IN];
    const int n = blockIdx.x, f = threadIdx.x;
    if (f < F_IN) arow[f] = A[n * F_IN + f];
    __syncthreads();
    float acc = bias[f];
    #pragma unroll
    for (int k = 0; k < F_IN; ++k) acc = fmaf(arow[k], W[k * F_OUT + f], acc);
    out[n * F_OUT + f] = fmaxf(acc, 0.0f);
}

extern "C" void kernel_launch(void* const* d_in, const int* in_sizes, int n_in,
                              void* d_out, int out_size, void* d_ws, size_t ws_size,
                              hipStream_t stream) {
    const float* X    = (const float*)d_in[0];
    const int*   ei   = (const int*)  d_in[1];
    const float* ew   = (const float*)d_in[2];
    const float* W    = (const float*)d_in[3];
    const float* bias = (const float*)d_in[4];
    float*       out  = (float*)d_out;

    const size_t pack4_bytes = (size_t)NBKT * CAP2 * 4;                    // 14.8 MB
    const size_t xh_bytes    = (size_t)N_NODES * F_IN * 2;                 // 12.8 MB
    const size_t ah_bytes    = (size_t)N_NODES * F_IN * 2;                 // 12.8 MB
    const size_t nbase_bytes = (size_t)N_NODES * 4;
    const size_t ndeg_bytes  = (size_t)N_NODES * 4;
    const size_t dloc_bytes  = (size_t)NBKT * CAP2;                        // 3.7 MB
    const size_t bcnt_bytes  = (size_t)NBKT * 4;
    const size_t need = pack4_bytes + xh_bytes + ah_bytes + nbase_bytes +
                        ndeg_bytes + dloc_bytes + bcnt_bytes;

    if (ws_size >= need) {
        char* p = (char*)d_ws;
        unsigned*       pack4 = (unsigned*)p;       p += pack4_bytes;
        unsigned short* Xh    = (unsigned short*)p; p += xh_bytes;
        unsigned short* Ah    = (unsigned short*)p; p += ah_bytes;
        unsigned*       nbase = (unsigned*)p;       p += nbase_bytes;
        unsigned*       ndeg  = (unsigned*)p;       p += ndeg_bytes;
        unsigned char*  dloc8 = (unsigned char*)p;  p += dloc_bytes;
        unsigned*       bcur  = (unsigned*)p;       p += bcnt_bytes;

        hipMemsetAsync(bcur, 0, bcnt_bytes, stream);
        k_part<<<PART_BLOCKS, PART_THREADS, 0, stream>>>(X, Xh, ei, ew, bcur, pack4, dloc8);
        k_sort<<<NBKT, SORT_THREADS, 0, stream>>>(pack4, dloc8, bcur, nbase, ndeg);
        k_gather<<<N_NODES / 4, 256, 0, stream>>>(Xh, pack4, nbase, ndeg, Ah);
        k_proj<<<N_NODES / 16, 256, 0, stream>>>(Ah, W, bias, out);
    } else {
        float* A = (float*)d_ws;   // 25.6 MB
        hipMemsetAsync(A, 0, (size_t)N_NODES * F_IN * sizeof(float), stream);
        gcn_scatter_fb<<<4096, 256, 0, stream>>>(X, ei, ew, A);
        gcn_proj_fb<<<N_NODES, 128, 0, stream>>>(A, W, bias, out);
    }
}

// Round 18
// 137.747 us; speedup vs baseline: 1.0413x; 1.0413x over previous
//
#include <hip/hip_runtime.h>

#define N_NODES 100000
#define N_EDGES 3200000
#define F_IN 64
#define F_OUT 128

#define BSHIFT 7
#define BKT_NODES 128                                   // nodes per bucket
#define NBKT ((N_NODES + BKT_NODES - 1) / BKT_NODES)    // 782
#define CAP2 4736                                       // mean 4096 + 10 sigma

#define PART_BLOCKS 256
#define PART_THREADS 1024
#define CHUNK (N_EDGES / PART_BLOCKS)                   // 12500 exactly
#define PRPT ((CHUNK + PART_THREADS - 1) / PART_THREADS) // 13

#define SORT_THREADS 512
#define RPT 10                                          // ceil(CAP2/512)

__device__ __forceinline__ unsigned short f2bf(float f) {
    unsigned x = __float_as_uint(f);
    return (unsigned short)((x + 0x7FFFu + ((x >> 16) & 1u)) >> 16);   // RNE
}
__device__ __forceinline__ float bf2f(unsigned short h) {
    return __uint_as_float(((unsigned)h) << 16);
}
__device__ __forceinline__ unsigned bf15(float f) {      // w in [0,1): sign bit 0
    unsigned x = __float_as_uint(f);
    return ((x + 0x7FFFu + ((x >> 16) & 1u)) >> 16) & 0x7FFFu;
}

// ---- Phase 1: X->bf16 slice + bucket partition with in-LDS block sort -------
// (round-12/15 proven config: 256 blocks x 1024 threads)
__global__ __launch_bounds__(PART_THREADS) void k_part(const float* __restrict__ X,
                                                       unsigned short* __restrict__ Xh,
                                                       const int* __restrict__ ei,
                                                       const float* __restrict__ ew,
                                                       unsigned* __restrict__ bcur,
                                                       unsigned* __restrict__ pack4,
                                                       unsigned char* __restrict__ dloc8) {
    __shared__ unsigned spack[CHUNK];                    // 50 KB
    __shared__ unsigned short sbkt[CHUNK];               // 25 KB
    __shared__ unsigned char  sdl[CHUNK];                // 12.5 KB
    __shared__ unsigned pcnt[NBKT];
    __shared__ unsigned lstart[NBKT];
    __shared__ unsigned lcur[NBKT];
    __shared__ unsigned rbase[NBKT];
    __shared__ unsigned sscan[PART_THREADS];             // 4 KB
    const int t = threadIdx.x;
    const int e0 = blockIdx.x * CHUNK;

    // phase 0: convert this block's 1/256 slice of X to bf16
    {
        const int per = (N_NODES * F_IN / 4) / PART_BLOCKS;   // 6250 float4s
        const int s0 = blockIdx.x * per;
        for (int i = t; i < per; i += PART_THREADS) {
            float4 v = ((const float4*)X)[s0 + i];
            ushort4 h;
            h.x = f2bf(v.x); h.y = f2bf(v.y); h.z = f2bf(v.z); h.w = f2bf(v.w);
            ((ushort4*)Xh)[s0 + i] = h;
        }
    }

    for (int i = t; i < NBKT; i += PART_THREADS) { pcnt[i] = 0u; lcur[i] = 0u; }
    __syncthreads();

    unsigned rp[PRPT], rm[PRPT];
    #pragma unroll
    for (int j = 0; j < PRPT; ++j) {
        int i = t + j * PART_THREADS;
        if (i < CHUNK) {
            int dst = __builtin_nontemporal_load(&ei[e0 + i]);
            int src = __builtin_nontemporal_load(&ei[N_EDGES + e0 + i]);
            float w = __builtin_nontemporal_load(&ew[e0 + i]);
            rp[j] = ((unsigned)src << 15) | bf15(w);
            unsigned b = (unsigned)dst >> BSHIFT;
            rm[j] = (b << 7) | ((unsigned)dst & (BKT_NODES - 1));
            atomicAdd(&pcnt[b], 1u);
        }
    }
    __syncthreads();

    unsigned v = (t < NBKT) ? pcnt[t] : 0u;
    sscan[t] = v;
    __syncthreads();
    for (int off = 1; off < PART_THREADS; off <<= 1) {
        unsigned u = (t >= off) ? sscan[t - off] : 0u;
        __syncthreads();
        sscan[t] += u;
        __syncthreads();
    }
    if (t < NBKT) {
        lstart[t] = sscan[t] - v;
        rbase[t]  = v ? atomicAdd(&bcur[t], v) : 0u;     // bulk reserve
    }
    __syncthreads();

    #pragma unroll
    for (int j = 0; j < PRPT; ++j) {
        int i = t + j * PART_THREADS;
        if (i < CHUNK) {
            unsigned b = rm[j] >> 7;
            unsigned slot = lstart[b] + atomicAdd(&lcur[b], 1u);
            spack[slot] = rp[j];
            sbkt[slot]  = (unsigned short)b;
            sdl[slot]   = (unsigned char)(rm[j] & (BKT_NODES - 1));
        }
    }
    __syncthreads();

    for (int i = t; i < CHUNK; i += PART_THREADS) {
        unsigned b = sbkt[i];
        unsigned dest = rbase[b] + ((unsigned)i - lstart[b]);
        if (dest < CAP2) {                               // overflow guard (p ~ 1e-18)
            pack4[(size_t)b * CAP2 + dest] = spack[i];
            dloc8[(size_t)b * CAP2 + dest] = sdl[i];
        }
    }
}

// ---- Phase 2: per-bucket node sort (packed recs, in place) ------------------
__global__ __launch_bounds__(SORT_THREADS) void k_sort(unsigned* __restrict__ pack4,
                                                       const unsigned char* __restrict__ dloc8,
                                                       const unsigned* __restrict__ bcnt,
                                                       unsigned* __restrict__ nbase,
                                                       unsigned* __restrict__ ndeg) {
    __shared__ unsigned srec[CAP2];                      // 18.9 KB
    __shared__ unsigned lcnt[BKT_NODES];
    __shared__ unsigned sincl[BKT_NODES];
    __shared__ unsigned lcur[BKT_NODES];
    const int t = threadIdx.x;
    const int b = blockIdx.x;
    unsigned cnt = bcnt[b];
    if (cnt > CAP2) cnt = CAP2;
    unsigned* run = pack4 + (size_t)b * CAP2;
    const unsigned char* drun = dloc8 + (size_t)b * CAP2;

    if (t < BKT_NODES) { lcnt[t] = 0u; lcur[t] = 0u; }
    __syncthreads();

    unsigned rp[RPT], rd[RPT];
    #pragma unroll
    for (int j = 0; j < RPT; ++j) {
        unsigned i = t + j * SORT_THREADS;
        if (i < cnt) {
            rp[j] = run[i];
            rd[j] = drun[i];
            atomicAdd(&lcnt[rd[j]], 1u);
        }
    }
    __syncthreads();

    if (t < BKT_NODES) sincl[t] = lcnt[t];
    __syncthreads();
    for (int off = 1; off < BKT_NODES; off <<= 1) {
        unsigned u = (t < BKT_NODES && t >= off) ? sincl[t - off] : 0u;
        __syncthreads();
        if (t < BKT_NODES) sincl[t] += u;
        __syncthreads();
    }

    #pragma unroll
    for (int j = 0; j < RPT; ++j) {
        unsigned i = t + j * SORT_THREADS;
        if (i < cnt) {
            unsigned nl = rd[j];
            unsigned slot = sincl[nl] - lcnt[nl] + atomicAdd(&lcur[nl], 1u);
            srec[slot] = rp[j];
        }
    }
    __syncthreads();

    for (unsigned i = t; i < cnt; i += SORT_THREADS) run[i] = srec[i];   // coalesced
    if (t < BKT_NODES) {
        int node = (b << BSHIFT) + t;
        if (node < N_NODES) {
            nbase[node] = (unsigned)b * CAP2 + sincl[t] - lcnt[t];       // uint units
            ndeg[node]  = lcnt[t];
        }
    }
}

// ---- Phase 3: one wave per node; 16-deep load pipeline ----------------------
__global__ __launch_bounds__(256) void k_gather(const unsigned short* __restrict__ Xh,
                                                const unsigned* __restrict__ recs,
                                                const unsigned* __restrict__ nbase,
                                                const unsigned* __restrict__ ndeg,
                                                unsigned short* __restrict__ Ah) {
    const int node = (blockIdx.x * 256 + threadIdx.x) >> 6;   // 25000*4 == N_NODES
    const int lane = threadIdx.x & 63;
    const unsigned i0 = nbase[node];
    const unsigned d  = ndeg[node];

    float acc = 0.f;
    if (d <= 64u) {                                      // wave-uniform branch (~always)
        unsigned p0 = 0u;
        if (lane < (int)d) p0 = recs[i0 + lane];         // one coalesced load
        for (unsigned i = 0; i < d; i += 16) {
            unsigned pk[16];
            #pragma unroll
            for (int q = 0; q < 16; ++q)
                pk[q] = (unsigned)__builtin_amdgcn_readlane((int)p0, (int)(i + q));
            float v[16];
            #pragma unroll
            for (int q = 0; q < 16; ++q)
                v[q] = bf2f(Xh[(size_t)(pk[q] >> 15) * F_IN + lane]);
            #pragma unroll
            for (int q = 0; q < 16; ++q)
                acc = fmaf(v[q], __uint_as_float((pk[q] & 0x7FFFu) << 16), acc);
        }
    } else {                                             // rare (P ~ 1e-8 per node)
        for (unsigned i = 0; i < d; ++i) {
            unsigned pk = recs[i0 + i];
            acc = fmaf(bf2f(Xh[(size_t)(pk >> 15) * F_IN + lane]),
                       __uint_as_float((pk & 0x7FFFu) << 16), acc);
        }
    }
    Ah[(size_t)node * F_IN + lane] = f2bf(acc);
}

// ---- Phase 4: projection + bias + ReLU, 16 nodes/block (bf16 A in) ----------
__global__ __launch_bounds__(256) void k_proj(const unsigned short* __restrict__ Ah,
                                              const float* __restrict__ W,
                                              const float* __restrict__ bias,
                                              float* __restrict__ out) {
    __shared__ float arows[16 * F_IN];                   // 4 KB
    const int t = threadIdx.x;
    const int node0 = blockIdx.x * 16;                   // 6250 blocks exactly
    {
        ushort4 h = ((const ushort4*)(Ah + (size_t)node0 * F_IN))[t];   // 256*4 = 1024
        float4 f;
        f.x = bf2f(h.x); f.y = bf2f(h.y); f.z = bf2f(h.z); f.w = bf2f(h.w);
        ((float4*)arows)[t] = f;
    }
    __syncthreads();

    const int f = t & 127;
    const int g = t >> 7;                                // 0..1, 8 nodes each
    float wcol[F_IN];
    #pragma unroll
    for (int k = 0; k < F_IN; ++k) wcol[k] = W[k * F_OUT + f];   // coalesced
    const float bf = bias[f];
    for (int n = g * 8; n < g * 8 + 8; ++n) {
        float acc = bf;
        #pragma unroll
        for (int k4 = 0; k4 < F_IN / 4; ++k4) {
            float4 a4 = *(const float4*)&arows[n * F_IN + k4 * 4];
            acc = fmaf(a4.x, wcol[k4 * 4 + 0], acc);
            acc = fmaf(a4.y, wcol[k4 * 4 + 1], acc);
            acc = fmaf(a4.z, wcol[k4 * 4 + 2], acc);
            acc = fmaf(a4.w, wcol[k4 * 4 + 3], acc);
        }
        out[(size_t)(node0 + n) * F_OUT + f] = fmaxf(acc, 0.f);
    }
}

// ---------------- Fallback (round-1 path) if workspace too small --------------
__global__ __launch_bounds__(256) void gcn_scatter_fb(const float* __restrict__ X,
                                                      const int* __restrict__ ei,
                                                      const float* __restrict__ ew,
                                                      float* __restrict__ A) {
    const int lane = threadIdx.x & 63;
    const int wave = (blockIdx.x * blockDim.x + threadIdx.x) >> 6;
    const int nW = (gridDim.x * blockDim.x) >> 6;
    for (int e = wave; e < N_EDGES; e += nW) {
        const int dst = ei[e];
        const int src = ei[N_EDGES + e];
        atomicAdd(&A[dst * F_IN + lane], X[src * F_IN + lane] * ew[e]);
    }
}
__global__ __launch_bounds__(128) void gcn_proj_fb(const float* __restrict__ A,
                                                   const float* __restrict__ W,
                                                   const float* __restrict__ bias,
                                                   float* __restrict__ out) {
    __shared__ float arow[F_IN];
    const int n = blockIdx.x, f = threadIdx.x;
    if (f < F_IN) arow[f] = A[n * F_IN + f];
    __syncthreads();
    float acc = bias[f];
    #pragma unroll
    for (int k = 0; k < F_IN; ++k) acc = fmaf(arow[k], W[k * F_OUT + f], acc);
    out[n * F_OUT + f] = fmaxf(acc, 0.0f);
}

extern "C" void kernel_launch(void* const* d_in, const int* in_sizes, int n_in,
                              void* d_out, int out_size, void* d_ws, size_t ws_size,
                              hipStream_t stream) {
    const float* X    = (const float*)d_in[0];
    const int*   ei   = (const int*)  d_in[1];
    const float* ew   = (const float*)d_in[2];
    const float* W    = (const float*)d_in[3];
    const float* bias = (const float*)d_in[4];
    float*       out  = (float*)d_out;

    const size_t pack4_bytes = (size_t)NBKT * CAP2 * 4;                    // 14.8 MB
    const size_t xh_bytes    = (size_t)N_NODES * F_IN * 2;                 // 12.8 MB
    const size_t ah_bytes    = (size_t)N_NODES * F_IN * 2;                 // 12.8 MB
    const size_t nbase_bytes = (size_t)N_NODES * 4;
    const size_t ndeg_bytes  = (size_t)N_NODES * 4;
    const size_t dloc_bytes  = (size_t)NBKT * CAP2;                        // 3.7 MB
    const size_t bcnt_bytes  = (size_t)NBKT * 4;
    const size_t need = pack4_bytes + xh_bytes + ah_bytes + nbase_bytes +
                        ndeg_bytes + dloc_bytes + bcnt_bytes;

    if (ws_size >= need) {
        char* p = (char*)d_ws;
        unsigned*       pack4 = (unsigned*)p;       p += pack4_bytes;
        unsigned short* Xh    = (unsigned short*)p; p += xh_bytes;
        unsigned short* Ah    = (unsigned short*)p; p += ah_bytes;
        unsigned*       nbase = (unsigned*)p;       p += nbase_bytes;
        unsigned*       ndeg  = (unsigned*)p;       p += ndeg_bytes;
        unsigned char*  dloc8 = (unsigned char*)p;  p += dloc_bytes;
        unsigned*       bcur  = (unsigned*)p;       p += bcnt_bytes;

        hipMemsetAsync(bcur, 0, bcnt_bytes, stream);
        k_part<<<PART_BLOCKS, PART_THREADS, 0, stream>>>(X, Xh, ei, ew, bcur, pack4, dloc8);
        k_sort<<<NBKT, SORT_THREADS, 0, stream>>>(pack4, dloc8, bcur, nbase, ndeg);
        k_gather<<<N_NODES / 4, 256, 0, stream>>>(Xh, pack4, nbase, ndeg, Ah);
        k_proj<<<N_NODES / 16, 256, 0, stream>>>(Ah, W, bias, out);
    } else {
        float* A = (float*)d_ws;   // 25.6 MB
        hipMemsetAsync(A, 0, (size_t)N_NODES * F_IN * sizeof(float), stream);
        gcn_scatter_fb<<<4096, 256, 0, stream>>>(X, ei, ew, A);
        gcn_proj_fb<<<N_NODES, 128, 0, stream>>>(A, W, bias, out);
    }
}